// Round 2
// baseline (807.526 us; speedup 1.0000x reference)
//
#include <hip/hip_runtime.h>
#include <math.h>

#define H1 56
#define W1 56
#define BB 16
#define NN 32
#define CC 512
#define MH 60
#define MW 60
#define OH 224
#define OW 224

typedef __bf16 bf16x8 __attribute__((ext_vector_type(8)));
typedef float floatx4 __attribute__((ext_vector_type(4)));

// ---------------- ws layout (float offsets) ----------------
#define XN_OFF   0
#define YN_OFF   50176
#define BEST_OFF 165376
#define UP_OFF   215552
#define TMP_OFF  1018368

// ---------------- norms: one wave per 512-vector ----------------
__global__ void norm_kernel(const float* __restrict__ src, float* __restrict__ dst, int nvec) {
    int wid  = (int)((blockIdx.x * blockDim.x + threadIdx.x) >> 6);
    int lane = threadIdx.x & 63;
    if (wid >= nvec) return;
    const float* p = src + (size_t)wid * CC + lane * 8;
    floatx4 a = *(const floatx4*)p;
    floatx4 b = *(const floatx4*)(p + 4);
    float s = a.x*a.x + a.y*a.y + a.z*a.z + a.w*a.w
            + b.x*b.x + b.y*b.y + b.z*b.z + b.w*b.w;
    s += __shfl_xor(s, 32, 64);
    s += __shfl_xor(s, 16, 64);
    s += __shfl_xor(s, 8, 64);
    s += __shfl_xor(s, 4, 64);
    s += __shfl_xor(s, 2, 64);
    s += __shfl_xor(s, 1, 64);
    if (lane == 0) dst[wid] = s;
}

// ---------------- main distance kernel ----------------
// grid: 56 * 14 blocks; block: 256 threads (4 waves). wave w owns emb pos (h, w0+w).
#define BSTRIDE 520   // 512 + 8 bf16 pad: 2-way-only LDS bank aliasing (free)

__global__ __launch_bounds__(256) void dist_kernel(
        const float* __restrict__ emb, const float* __restrict__ mb,
        const float* __restrict__ xnorm, const float* __restrict__ ynorm,
        float* __restrict__ best) {
    __shared__ __bf16 Bs[NN * BSTRIDE];

    int bx   = blockIdx.x;
    int h    = bx / 14;
    int w0   = (bx % 14) * 4;
    int tid  = threadIdx.x;
    int wave = tid >> 6;
    int lane = tid & 63;
    int nrow = lane & 15;     // A-row m for a-frag; B col n for b-frag & C col
    int seg  = lane >> 4;     // k-segment quad; C row group
    int w    = w0 + wave;     // this wave's emb position

    // ---- load A fragments (16 K-steps), fp32 -> bf16 in regs ----
    bf16x8 afrag[16];
    const float* ap = emb + ((size_t)(h * W1 + w) * BB + nrow) * CC + seg * 8;
#pragma unroll
    for (int kk = 0; kk < 16; kk++) {
        floatx4 f0 = *(const floatx4*)(ap + kk * 32);
        floatx4 f1 = *(const floatx4*)(ap + kk * 32 + 4);
        bf16x8 v;
        v[0] = (__bf16)f0.x; v[1] = (__bf16)f0.y; v[2] = (__bf16)f0.z; v[3] = (__bf16)f0.w;
        v[4] = (__bf16)f1.x; v[5] = (__bf16)f1.y; v[6] = (__bf16)f1.z; v[7] = (__bf16)f1.w;
        afrag[kk] = v;
    }
    floatx4 xn = *(const floatx4*)(xnorm + (size_t)(h * W1 + w) * BB + seg * 4);

    float bestv[4] = {1e30f, 1e30f, 1e30f, 1e30f};

    for (int d1 = 0; d1 < 5; d1++) {
        int mr = h + d1;
        for (int j = 0; j < 8; j++) {
            int mc = w0 + j;
            const float* bp = mb + (size_t)(mr * MW + mc) * NN * CC;
            __syncthreads();
            // stage 32x512 fp32 -> bf16 LDS, coalesced 32B/lane chunks
#pragma unroll
            for (int t = 0; t < 8; t++) {
                int c0 = t * 256 + tid;
                int n  = c0 >> 6;
                int ks = (c0 & 63) << 3;
                floatx4 f0 = *(const floatx4*)(bp + n * CC + ks);
                floatx4 f1 = *(const floatx4*)(bp + n * CC + ks + 4);
                bf16x8 v;
                v[0] = (__bf16)f0.x; v[1] = (__bf16)f0.y; v[2] = (__bf16)f0.z; v[3] = (__bf16)f0.w;
                v[4] = (__bf16)f1.x; v[5] = (__bf16)f1.y; v[6] = (__bf16)f1.z; v[7] = (__bf16)f1.w;
                *(bf16x8*)(&Bs[n * BSTRIDE + ks]) = v;
            }
            __syncthreads();

            int d2 = j - wave;
            if (d2 >= 0 && d2 < 5) {
                float yn0 = ynorm[(size_t)(mr * MW + mc) * NN + nrow];
                float yn1 = ynorm[(size_t)(mr * MW + mc) * NN + nrow + 16];
                floatx4 acc0 = {0.f, 0.f, 0.f, 0.f};
                floatx4 acc1 = {0.f, 0.f, 0.f, 0.f};
#pragma unroll
                for (int kk = 0; kk < 16; kk++) {
                    bf16x8 b0 = *(const bf16x8*)(&Bs[nrow * BSTRIDE + kk * 32 + seg * 8]);
                    bf16x8 b1 = *(const bf16x8*)(&Bs[(nrow + 16) * BSTRIDE + kk * 32 + seg * 8]);
                    acc0 = __builtin_amdgcn_mfma_f32_16x16x32_bf16(afrag[kk], b0, acc0, 0, 0, 0);
                    acc1 = __builtin_amdgcn_mfma_f32_16x16x32_bf16(afrag[kk], b1, acc1, 0, 0, 0);
                }
#pragma unroll
                for (int r = 0; r < 4; r++) {
                    float d0 = fmaxf(xn[r] - 2.f * acc0[r] + yn0, 0.f);
                    float d1v = fmaxf(xn[r] - 2.f * acc1[r] + yn1, 0.f);
                    bestv[r] = fminf(bestv[r], fminf(d0, d1v));
                }
            }
        }
    }

    // reduce min over the 16 lanes (n-cols) of each quad-group
#pragma unroll
    for (int r = 0; r < 4; r++) {
        float v = bestv[r];
        v = fminf(v, __shfl_xor(v, 1, 64));
        v = fminf(v, __shfl_xor(v, 2, 64));
        v = fminf(v, __shfl_xor(v, 4, 64));
        v = fminf(v, __shfl_xor(v, 8, 64));
        bestv[r] = v;
    }
    if ((lane & 15) == 0) {
        int pos = h * W1 + w;
#pragma unroll
        for (int r = 0; r < 4; r++) {
            int b = seg * 4 + r;
            best[(size_t)b * (H1 * W1) + pos] = sqrtf(bestv[r]);
        }
    }
}

// ---------------- img = per-batch max ----------------
__global__ void max_kernel(const float* __restrict__ best, float* __restrict__ out) {
    __shared__ float red[256];
    int b = blockIdx.x;
    float m = 0.f;  // distances >= 0
    for (int i = threadIdx.x; i < H1 * W1; i += 256)
        m = fmaxf(m, best[(size_t)b * (H1 * W1) + i]);
    red[threadIdx.x] = m;
    __syncthreads();
    for (int s = 128; s > 0; s >>= 1) {
        if (threadIdx.x < s) red[threadIdx.x] = fmaxf(red[threadIdx.x], red[threadIdx.x + s]);
        __syncthreads();
    }
    if (threadIdx.x == 0) out[b] = red[0];
}

// ---------------- bilinear 4x upsample (half-pixel, edge clamp) ----------------
__global__ void up_kernel(const float* __restrict__ best, float* __restrict__ up) {
    int idx = blockIdx.x * 256 + threadIdx.x;
    int x = idx % OW;
    int y = (idx / OW) % OH;
    int b = idx / (OW * OH);
    const float fr[4] = {0.625f, 0.875f, 0.125f, 0.375f};

    int qy = y >> 2, ry = y & 3;
    int ly = qy + ((ry < 2) ? -1 : 0);
    float ty = fr[ry];
    int hy = min(ly + 1, H1 - 1); ly = max(ly, 0);

    int qx = x >> 2, rx = x & 3;
    int lx = qx + ((rx < 2) ? -1 : 0);
    float tx = fr[rx];
    int hx = min(lx + 1, W1 - 1); lx = max(lx, 0);

    const float* p = best + (size_t)b * (H1 * W1);
    float v00 = p[ly * W1 + lx], v01 = p[ly * W1 + hx];
    float v10 = p[hy * W1 + lx], v11 = p[hy * W1 + hx];
    up[idx] = (1.f - ty) * ((1.f - tx) * v00 + tx * v01)
            + ty * ((1.f - tx) * v10 + tx * v11);
}

// ---------------- separable gaussian blur, reflect pad ----------------
struct GaussK { float k[33]; };

__device__ __forceinline__ int refl(int i, int n) {
    i = (i < 0) ? -i : i;
    i = (i > n - 1) ? 2 * (n - 1) - i : i;
    return i;
}

__global__ void blurh_kernel(const float* __restrict__ src, float* __restrict__ dst, GaussK g) {
    int idx = blockIdx.x * 256 + threadIdx.x;
    int x = idx % OW;
    int y = (idx / OW) % OH;
    int b = idx / (OW * OH);
    const float* p = src + (size_t)b * OH * OW;
    float acc = 0.f;
#pragma unroll
    for (int u = 0; u < 33; u++) {
        int yy = refl(y - 16 + u, OH);
        acc += g.k[u] * p[yy * OW + x];
    }
    dst[idx] = acc;
}

__global__ void blurw_kernel(const float* __restrict__ src, float* __restrict__ dst, GaussK g) {
    int idx = blockIdx.x * 256 + threadIdx.x;
    int x = idx % OW;
    int y = (idx / OW) % OH;
    int b = idx / (OW * OH);
    const float* p = src + (size_t)b * OH * OW + (size_t)y * OW;
    float acc = 0.f;
#pragma unroll
    for (int u = 0; u < 33; u++) {
        int xx = refl(x - 16 + u, OW);
        acc += g.k[u] * p[xx];
    }
    dst[idx] = acc;
}

extern "C" void kernel_launch(void* const* d_in, const int* in_sizes, int n_in,
                              void* d_out, int out_size, void* d_ws, size_t ws_size,
                              hipStream_t stream) {
    const float* emb = (const float*)d_in[0];
    const float* mbp = (const float*)d_in[1];
    float* ws    = (float*)d_ws;
    float* xnorm = ws + XN_OFF;
    float* ynorm = ws + YN_OFF;
    float* best  = ws + BEST_OFF;
    float* up    = ws + UP_OFF;
    float* tmp   = ws + TMP_OFF;
    float* out   = (float*)d_out;

    // norms (exact fp32): ONE WAVE PER VECTOR -> nvec/4 blocks of 256 (4 waves/block)
    norm_kernel<<<(H1 * W1 * BB) / 4, 256, 0, stream>>>(emb, xnorm, H1 * W1 * BB);
    norm_kernel<<<(MH * MW * NN) / 4, 256, 0, stream>>>(mbp, ynorm, MH * MW * NN);

    // main windowed min-distance
    dist_kernel<<<H1 * 14, 256, 0, stream>>>(emb, mbp, xnorm, ynorm, best);

    // img = per-batch max
    max_kernel<<<BB, 256, 0, stream>>>(best, out);

    // upsample + blur
    up_kernel<<<(BB * OH * OW) / 256, 256, 0, stream>>>(best, up);

    GaussK g;
    {
        double wsum = 0.0, wd[33];
        for (int u = 0; u < 33; u++) {
            double xk = (u - 16) / 4.0;
            wd[u] = exp(-0.5 * xk * xk);
            wsum += wd[u];
        }
        for (int u = 0; u < 33; u++) g.k[u] = (float)(wd[u] / wsum);
    }
    blurh_kernel<<<(BB * OH * OW) / 256, 256, 0, stream>>>(up, tmp, g);
    blurw_kernel<<<(BB * OH * OW) / 256, 256, 0, stream>>>(tmp, out + 16, g);
}

// Round 3
// 582.395 us; speedup vs baseline: 1.3866x; 1.3866x over previous
//
#include <hip/hip_runtime.h>
#include <math.h>

#define H1 56
#define W1 56
#define BB 16
#define NN 32
#define CC 512
#define MH 60
#define MW 60
#define OH 224
#define OW 224

typedef __bf16 bf16x8 __attribute__((ext_vector_type(8)));
typedef float floatx4 __attribute__((ext_vector_type(4)));

// ---------------- ws layout (float offsets), bf16 fast path ----------------
// mbh  : 60*60*32*512 bf16  = 29491200 floats
// embh : 56*56*16*512 bf16  = 12845056 floats
#define MBH_OFF   0
#define EMBH_OFF  29491200
#define F_XN_OFF  42336256
#define F_YN_OFF  42386432
#define F_BEST_OFF 42501632
#define F_UP_OFF  42551808
#define F_TMP_OFF 43354624
#define F_TOTAL_FLOATS 44157440ull   // *4 = 176.6 MB

// ---------------- fallback layout (fp32 path, 7.3 MB) ----------------
#define S_XN_OFF   0
#define S_YN_OFF   50176
#define S_BEST_OFF 165376
#define S_UP_OFF   215552
#define S_TMP_OFF  1018368

// ---------------- convert + norm: one wave per 512-vector ----------------
// dsth == nullptr -> norm only (fallback path)
__global__ void cvt_norm_kernel(const float* __restrict__ src, __bf16* __restrict__ dsth,
                                float* __restrict__ norm, int nvec) {
    int wid  = (int)((blockIdx.x * blockDim.x + threadIdx.x) >> 6);
    int lane = threadIdx.x & 63;
    if (wid >= nvec) return;
    const float* p = src + (size_t)wid * CC + lane * 8;
    floatx4 a = *(const floatx4*)p;
    floatx4 b = *(const floatx4*)(p + 4);
    if (dsth) {
        bf16x8 v;
        v[0] = (__bf16)a.x; v[1] = (__bf16)a.y; v[2] = (__bf16)a.z; v[3] = (__bf16)a.w;
        v[4] = (__bf16)b.x; v[5] = (__bf16)b.y; v[6] = (__bf16)b.z; v[7] = (__bf16)b.w;
        *(bf16x8*)(dsth + (size_t)wid * CC + lane * 8) = v;
    }
    float s = a.x*a.x + a.y*a.y + a.z*a.z + a.w*a.w
            + b.x*b.x + b.y*b.y + b.z*b.z + b.w*b.w;
    s += __shfl_xor(s, 32, 64);
    s += __shfl_xor(s, 16, 64);
    s += __shfl_xor(s, 8, 64);
    s += __shfl_xor(s, 4, 64);
    s += __shfl_xor(s, 2, 64);
    s += __shfl_xor(s, 1, 64);
    if (lane == 0) norm[wid] = s;
}

#define BSTRIDE 520   // bf16 elems; 1040 B stride -> 2-way-only LDS aliasing (free, measured R2)

// ---------------- main distance kernel, bf16 inputs (fast path) ----------------
// grid: 56*14 blocks; 256 threads = 4 waves; wave w owns emb pos (h, w0+w).
// LDS 33.3 KB single-buffer -> 4 blocks/CU -> all 784 blocks co-resident.
__global__ __launch_bounds__(256, 4) void dist_kernel_bf16(
        const __bf16* __restrict__ embh, const __bf16* __restrict__ mbh,
        const float* __restrict__ xnorm, const float* __restrict__ ynorm,
        float* __restrict__ best) {
    __shared__ __bf16 Bs[NN * BSTRIDE];

    int bx   = blockIdx.x;
    int h    = bx / 14;
    int w0   = (bx % 14) * 4;
    int tid  = threadIdx.x;
    int wave = tid >> 6;
    int lane = tid & 63;
    int nrow = lane & 15;
    int seg  = lane >> 4;
    int w    = w0 + wave;

    // A fragments: 16 x 16B bf16 loads, stride 64B
    bf16x8 afrag[16];
    const __bf16* ap = embh + ((size_t)(h * W1 + w) * BB + nrow) * CC + seg * 8;
#pragma unroll
    for (int kk = 0; kk < 16; kk++)
        afrag[kk] = *(const bf16x8*)(ap + kk * 32);
    floatx4 xn = *(const floatx4*)(xnorm + (size_t)(h * W1 + w) * BB + seg * 4);

    float bestv[4] = {1e30f, 1e30f, 1e30f, 1e30f};

    for (int d1 = 0; d1 < 5; d1++) {
        int mr = h + d1;
        for (int j = 0; j < 8; j++) {
            int mc = w0 + j;
            const __bf16* bp = mbh + (size_t)(mr * MW + mc) * NN * CC;
            __syncthreads();
            // stage 32x512 bf16 -> LDS: 2048 16B-chunks, 8 per thread
#pragma unroll
            for (int t = 0; t < 8; t++) {
                int s  = t * 256 + tid;
                int n  = s >> 6;        // 64 chunks per n-row
                int ch = s & 63;
                *(bf16x8*)(&Bs[n * BSTRIDE + ch * 8]) = *(const bf16x8*)(bp + n * CC + ch * 8);
            }
            __syncthreads();

            int d2 = j - wave;
            if (d2 >= 0 && d2 < 5) {
                float yn0 = ynorm[(size_t)(mr * MW + mc) * NN + nrow];
                float yn1 = ynorm[(size_t)(mr * MW + mc) * NN + nrow + 16];
                floatx4 acc0 = {0.f, 0.f, 0.f, 0.f};
                floatx4 acc1 = {0.f, 0.f, 0.f, 0.f};
#pragma unroll
                for (int kk = 0; kk < 16; kk++) {
                    bf16x8 b0 = *(const bf16x8*)(&Bs[nrow * BSTRIDE + kk * 32 + seg * 8]);
                    bf16x8 b1 = *(const bf16x8*)(&Bs[(nrow + 16) * BSTRIDE + kk * 32 + seg * 8]);
                    acc0 = __builtin_amdgcn_mfma_f32_16x16x32_bf16(afrag[kk], b0, acc0, 0, 0, 0);
                    acc1 = __builtin_amdgcn_mfma_f32_16x16x32_bf16(afrag[kk], b1, acc1, 0, 0, 0);
                }
#pragma unroll
                for (int r = 0; r < 4; r++) {
                    float d0  = fmaxf(xn[r] - 2.f * acc0[r] + yn0, 0.f);
                    float d1v = fmaxf(xn[r] - 2.f * acc1[r] + yn1, 0.f);
                    bestv[r] = fminf(bestv[r], fminf(d0, d1v));
                }
            }
        }
    }

#pragma unroll
    for (int r = 0; r < 4; r++) {
        float v = bestv[r];
        v = fminf(v, __shfl_xor(v, 1, 64));
        v = fminf(v, __shfl_xor(v, 2, 64));
        v = fminf(v, __shfl_xor(v, 4, 64));
        v = fminf(v, __shfl_xor(v, 8, 64));
        bestv[r] = v;
    }
    if ((lane & 15) == 0) {
        int pos = h * W1 + w;
#pragma unroll
        for (int r = 0; r < 4; r++) {
            int b = seg * 4 + r;
            best[(size_t)b * (H1 * W1) + pos] = sqrtf(bestv[r]);
        }
    }
}

// ---------------- fallback: fp32-staging dist (proven R2) ----------------
__global__ __launch_bounds__(256) void dist_kernel_f32(
        const float* __restrict__ emb, const float* __restrict__ mb,
        const float* __restrict__ xnorm, const float* __restrict__ ynorm,
        float* __restrict__ best) {
    __shared__ __bf16 Bs[NN * BSTRIDE];

    int bx   = blockIdx.x;
    int h    = bx / 14;
    int w0   = (bx % 14) * 4;
    int tid  = threadIdx.x;
    int wave = tid >> 6;
    int lane = tid & 63;
    int nrow = lane & 15;
    int seg  = lane >> 4;
    int w    = w0 + wave;

    bf16x8 afrag[16];
    const float* ap = emb + ((size_t)(h * W1 + w) * BB + nrow) * CC + seg * 8;
#pragma unroll
    for (int kk = 0; kk < 16; kk++) {
        floatx4 f0 = *(const floatx4*)(ap + kk * 32);
        floatx4 f1 = *(const floatx4*)(ap + kk * 32 + 4);
        bf16x8 v;
        v[0] = (__bf16)f0.x; v[1] = (__bf16)f0.y; v[2] = (__bf16)f0.z; v[3] = (__bf16)f0.w;
        v[4] = (__bf16)f1.x; v[5] = (__bf16)f1.y; v[6] = (__bf16)f1.z; v[7] = (__bf16)f1.w;
        afrag[kk] = v;
    }
    floatx4 xn = *(const floatx4*)(xnorm + (size_t)(h * W1 + w) * BB + seg * 4);

    float bestv[4] = {1e30f, 1e30f, 1e30f, 1e30f};

    for (int d1 = 0; d1 < 5; d1++) {
        int mr = h + d1;
        for (int j = 0; j < 8; j++) {
            int mc = w0 + j;
            const float* bp = mb + (size_t)(mr * MW + mc) * NN * CC;
            __syncthreads();
#pragma unroll
            for (int t = 0; t < 8; t++) {
                int c0 = t * 256 + tid;
                int n  = c0 >> 6;
                int ks = (c0 & 63) << 3;
                floatx4 f0 = *(const floatx4*)(bp + n * CC + ks);
                floatx4 f1 = *(const floatx4*)(bp + n * CC + ks + 4);
                bf16x8 v;
                v[0] = (__bf16)f0.x; v[1] = (__bf16)f0.y; v[2] = (__bf16)f0.z; v[3] = (__bf16)f0.w;
                v[4] = (__bf16)f1.x; v[5] = (__bf16)f1.y; v[6] = (__bf16)f1.z; v[7] = (__bf16)f1.w;
                *(bf16x8*)(&Bs[n * BSTRIDE + ks]) = v;
            }
            __syncthreads();

            int d2 = j - wave;
            if (d2 >= 0 && d2 < 5) {
                float yn0 = ynorm[(size_t)(mr * MW + mc) * NN + nrow];
                float yn1 = ynorm[(size_t)(mr * MW + mc) * NN + nrow + 16];
                floatx4 acc0 = {0.f, 0.f, 0.f, 0.f};
                floatx4 acc1 = {0.f, 0.f, 0.f, 0.f};
#pragma unroll
                for (int kk = 0; kk < 16; kk++) {
                    bf16x8 b0 = *(const bf16x8*)(&Bs[nrow * BSTRIDE + kk * 32 + seg * 8]);
                    bf16x8 b1 = *(const bf16x8*)(&Bs[(nrow + 16) * BSTRIDE + kk * 32 + seg * 8]);
                    acc0 = __builtin_amdgcn_mfma_f32_16x16x32_bf16(afrag[kk], b0, acc0, 0, 0, 0);
                    acc1 = __builtin_amdgcn_mfma_f32_16x16x32_bf16(afrag[kk], b1, acc1, 0, 0, 0);
                }
#pragma unroll
                for (int r = 0; r < 4; r++) {
                    float d0  = fmaxf(xn[r] - 2.f * acc0[r] + yn0, 0.f);
                    float d1v = fmaxf(xn[r] - 2.f * acc1[r] + yn1, 0.f);
                    bestv[r] = fminf(bestv[r], fminf(d0, d1v));
                }
            }
        }
    }

#pragma unroll
    for (int r = 0; r < 4; r++) {
        float v = bestv[r];
        v = fminf(v, __shfl_xor(v, 1, 64));
        v = fminf(v, __shfl_xor(v, 2, 64));
        v = fminf(v, __shfl_xor(v, 4, 64));
        v = fminf(v, __shfl_xor(v, 8, 64));
        bestv[r] = v;
    }
    if ((lane & 15) == 0) {
        int pos = h * W1 + w;
#pragma unroll
        for (int r = 0; r < 4; r++) {
            int b = seg * 4 + r;
            best[(size_t)b * (H1 * W1) + pos] = sqrtf(bestv[r]);
        }
    }
}

// ---------------- img = per-batch max ----------------
__global__ void max_kernel(const float* __restrict__ best, float* __restrict__ out) {
    __shared__ float red[256];
    int b = blockIdx.x;
    float m = 0.f;
    for (int i = threadIdx.x; i < H1 * W1; i += 256)
        m = fmaxf(m, best[(size_t)b * (H1 * W1) + i]);
    red[threadIdx.x] = m;
    __syncthreads();
    for (int s = 128; s > 0; s >>= 1) {
        if (threadIdx.x < s) red[threadIdx.x] = fmaxf(red[threadIdx.x], red[threadIdx.x + s]);
        __syncthreads();
    }
    if (threadIdx.x == 0) out[b] = red[0];
}

// ---------------- bilinear 4x upsample (half-pixel, edge clamp) ----------------
__global__ void up_kernel(const float* __restrict__ best, float* __restrict__ up) {
    int idx = blockIdx.x * 256 + threadIdx.x;
    int x = idx % OW;
    int y = (idx / OW) % OH;
    int b = idx / (OW * OH);
    const float fr[4] = {0.625f, 0.875f, 0.125f, 0.375f};

    int qy = y >> 2, ry = y & 3;
    int ly = qy + ((ry < 2) ? -1 : 0);
    float ty = fr[ry];
    int hy = min(ly + 1, H1 - 1); ly = max(ly, 0);

    int qx = x >> 2, rx = x & 3;
    int lx = qx + ((rx < 2) ? -1 : 0);
    float tx = fr[rx];
    int hx = min(lx + 1, W1 - 1); lx = max(lx, 0);

    const float* p = best + (size_t)b * (H1 * W1);
    float v00 = p[ly * W1 + lx], v01 = p[ly * W1 + hx];
    float v10 = p[hy * W1 + lx], v11 = p[hy * W1 + hx];
    up[idx] = (1.f - ty) * ((1.f - tx) * v00 + tx * v01)
            + ty * ((1.f - tx) * v10 + tx * v11);
}

// ---------------- separable gaussian blur, reflect pad ----------------
struct GaussK { float k[33]; };

__device__ __forceinline__ int refl(int i, int n) {
    i = (i < 0) ? -i : i;
    i = (i > n - 1) ? 2 * (n - 1) - i : i;
    return i;
}

__global__ void blurh_kernel(const float* __restrict__ src, float* __restrict__ dst, GaussK g) {
    int idx = blockIdx.x * 256 + threadIdx.x;
    int x = idx % OW;
    int y = (idx / OW) % OH;
    int b = idx / (OW * OH);
    const float* p = src + (size_t)b * OH * OW;
    float acc = 0.f;
#pragma unroll
    for (int u = 0; u < 33; u++) {
        int yy = refl(y - 16 + u, OH);
        acc += g.k[u] * p[yy * OW + x];
    }
    dst[idx] = acc;
}

__global__ void blurw_kernel(const float* __restrict__ src, float* __restrict__ dst, GaussK g) {
    int idx = blockIdx.x * 256 + threadIdx.x;
    int x = idx % OW;
    int y = (idx / OW) % OH;
    int b = idx / (OW * OH);
    const float* p = src + (size_t)b * OH * OW + (size_t)y * OW;
    float acc = 0.f;
#pragma unroll
    for (int u = 0; u < 33; u++) {
        int xx = refl(x - 16 + u, OW);
        acc += g.k[u] * p[xx];
    }
    dst[idx] = acc;
}

extern "C" void kernel_launch(void* const* d_in, const int* in_sizes, int n_in,
                              void* d_out, int out_size, void* d_ws, size_t ws_size,
                              hipStream_t stream) {
    const float* emb = (const float*)d_in[0];
    const float* mbp = (const float*)d_in[1];
    float* ws  = (float*)d_ws;
    float* out = (float*)d_out;

    bool big = ws_size >= F_TOTAL_FLOATS * 4ull;

    float* xnorm = ws + (big ? F_XN_OFF   : S_XN_OFF);
    float* ynorm = ws + (big ? F_YN_OFF   : S_YN_OFF);
    float* best  = ws + (big ? F_BEST_OFF : S_BEST_OFF);
    float* up    = ws + (big ? F_UP_OFF   : S_UP_OFF);
    float* tmp   = ws + (big ? F_TMP_OFF  : S_TMP_OFF);

    if (big) {
        __bf16* mbh  = (__bf16*)(ws + MBH_OFF);
        __bf16* embh = (__bf16*)(ws + EMBH_OFF);
        cvt_norm_kernel<<<(H1 * W1 * BB) / 4, 256, 0, stream>>>(emb, embh, xnorm, H1 * W1 * BB);
        cvt_norm_kernel<<<(MH * MW * NN) / 4, 256, 0, stream>>>(mbp, mbh, ynorm, MH * MW * NN);
        dist_kernel_bf16<<<H1 * 14, 256, 0, stream>>>(embh, mbh, xnorm, ynorm, best);
    } else {
        cvt_norm_kernel<<<(H1 * W1 * BB) / 4, 256, 0, stream>>>(emb, nullptr, xnorm, H1 * W1 * BB);
        cvt_norm_kernel<<<(MH * MW * NN) / 4, 256, 0, stream>>>(mbp, nullptr, ynorm, MH * MW * NN);
        dist_kernel_f32<<<H1 * 14, 256, 0, stream>>>(emb, mbp, xnorm, ynorm, best);
    }

    max_kernel<<<BB, 256, 0, stream>>>(best, out);
    up_kernel<<<(BB * OH * OW) / 256, 256, 0, stream>>>(best, up);

    GaussK g;
    {
        double wsum = 0.0, wd[33];
        for (int u = 0; u < 33; u++) {
            double xk = (u - 16) / 4.0;
            wd[u] = exp(-0.5 * xk * xk);
            wsum += wd[u];
        }
        for (int u = 0; u < 33; u++) g.k[u] = (float)(wd[u] / wsum);
    }
    blurh_kernel<<<(BB * OH * OW) / 256, 256, 0, stream>>>(up, tmp, g);
    blurw_kernel<<<(BB * OH * OW) / 256, 256, 0, stream>>>(tmp, out + 16, g);
}

// Round 4
// 523.113 us; speedup vs baseline: 1.5437x; 1.1133x over previous
//
#include <hip/hip_runtime.h>
#include <math.h>

#define H1 56
#define W1 56
#define BB 16
#define NN 32
#define CC 512
#define MH 60
#define MW 60
#define OH 224
#define OW 224

typedef __bf16 bf16x8 __attribute__((ext_vector_type(8)));
typedef float floatx4 __attribute__((ext_vector_type(4)));

// ---------------- ws layout (float offsets), bf16 fast path ----------------
#define MBH_OFF   0
#define EMBH_OFF  29491200
#define F_XN_OFF  42336256
#define F_YN_OFF  42386432
#define F_BEST_OFF 42501632
#define F_TMP1_OFF 42551808          // 16*224*56 = 200704 floats
#define F_TOTAL_FLOATS 44157440ull   // *4 = 176.6 MB

// ---------------- fallback layout (fp32 path) ----------------
#define S_XN_OFF   0
#define S_YN_OFF   50176
#define S_BEST_OFF 165376
#define S_TMP1_OFF 215552

// ---------------- convert + norm: one wave per 512-vector ----------------
__global__ void cvt_norm_kernel(const float* __restrict__ src, __bf16* __restrict__ dsth,
                                float* __restrict__ norm, int nvec) {
    int wid  = (int)((blockIdx.x * blockDim.x + threadIdx.x) >> 6);
    int lane = threadIdx.x & 63;
    if (wid >= nvec) return;
    const float* p = src + (size_t)wid * CC + lane * 8;
    floatx4 a = *(const floatx4*)p;
    floatx4 b = *(const floatx4*)(p + 4);
    if (dsth) {
        bf16x8 v;
        v[0] = (__bf16)a.x; v[1] = (__bf16)a.y; v[2] = (__bf16)a.z; v[3] = (__bf16)a.w;
        v[4] = (__bf16)b.x; v[5] = (__bf16)b.y; v[6] = (__bf16)b.z; v[7] = (__bf16)b.w;
        *(bf16x8*)(dsth + (size_t)wid * CC + lane * 8) = v;
    }
    float s = a.x*a.x + a.y*a.y + a.z*a.z + a.w*a.w
            + b.x*b.x + b.y*b.y + b.z*b.z + b.w*b.w;
    s += __shfl_xor(s, 32, 64);
    s += __shfl_xor(s, 16, 64);
    s += __shfl_xor(s, 8, 64);
    s += __shfl_xor(s, 4, 64);
    s += __shfl_xor(s, 2, 64);
    s += __shfl_xor(s, 1, 64);
    if (lane == 0) norm[wid] = s;
}

#define BSTRIDE 520   // bf16 elems; 2-way-only LDS aliasing (free)

// ---------------- main distance kernel: 2x4 emb tile ----------------
// grid 28*14; 256 thr = 4 waves; wave owns emb (h0, w0+wave) and (h0+1, w0+wave).
// mb rows h0..h0+5 x cols w0..w0+7 staged once each: 48 stages / 8 positions.
__global__ __launch_bounds__(256, 2) void dist_kernel_bf16(
        const __bf16* __restrict__ embh, const __bf16* __restrict__ mbh,
        const float* __restrict__ xnorm, const float* __restrict__ ynorm,
        float* __restrict__ best) {
    __shared__ __bf16 Bs[NN * BSTRIDE];

    int bx   = blockIdx.x;
    int h0   = (bx / 14) * 2;
    int w0   = (bx % 14) * 4;
    int tid  = threadIdx.x;
    int wave = tid >> 6;
    int lane = tid & 63;
    int nrow = lane & 15;
    int seg  = lane >> 4;
    int w    = w0 + wave;

    // A fragments for the two h-rows
    bf16x8 afragA[16], afragB[16];
    const __bf16* apA = embh + ((size_t)(h0 * W1 + w) * BB + nrow) * CC + seg * 8;
    const __bf16* apB = embh + ((size_t)((h0 + 1) * W1 + w) * BB + nrow) * CC + seg * 8;
#pragma unroll
    for (int kk = 0; kk < 16; kk++) {
        afragA[kk] = *(const bf16x8*)(apA + kk * 32);
        afragB[kk] = *(const bf16x8*)(apB + kk * 32);
    }
    floatx4 xnA = *(const floatx4*)(xnorm + (size_t)(h0 * W1 + w) * BB + seg * 4);
    floatx4 xnB = *(const floatx4*)(xnorm + (size_t)((h0 + 1) * W1 + w) * BB + seg * 4);

    float bvA[4] = {1e30f, 1e30f, 1e30f, 1e30f};
    float bvB[4] = {1e30f, 1e30f, 1e30f, 1e30f};

    for (int rr = 0; rr < 6; rr++) {
        int mr = h0 + rr;
        for (int j = 0; j < 8; j++) {
            int mc = w0 + j;
            const __bf16* bp = mbh + (size_t)(mr * MW + mc) * NN * CC;
            __syncthreads();
#pragma unroll
            for (int t = 0; t < 8; t++) {
                int s  = t * 256 + tid;
                int n  = s >> 6;
                int ch = s & 63;
                *(bf16x8*)(&Bs[n * BSTRIDE + ch * 8]) = *(const bf16x8*)(bp + n * CC + ch * 8);
            }
            __syncthreads();

            int d2 = j - wave;
            if (d2 >= 0 && d2 < 5) {
                bool a0 = (rr < 5);      // row h0 uses d1 = rr
                bool a1 = (rr >= 1);     // row h0+1 uses d1 = rr-1
                float yn0 = ynorm[(size_t)(mr * MW + mc) * NN + nrow];
                float yn1 = ynorm[(size_t)(mr * MW + mc) * NN + nrow + 16];
                if (a0 && a1) {
                    floatx4 c0 = {0,0,0,0}, c1 = {0,0,0,0}, c2 = {0,0,0,0}, c3 = {0,0,0,0};
#pragma unroll
                    for (int kk = 0; kk < 16; kk++) {
                        bf16x8 b0 = *(const bf16x8*)(&Bs[nrow * BSTRIDE + kk * 32 + seg * 8]);
                        bf16x8 b1 = *(const bf16x8*)(&Bs[(nrow + 16) * BSTRIDE + kk * 32 + seg * 8]);
                        c0 = __builtin_amdgcn_mfma_f32_16x16x32_bf16(afragA[kk], b0, c0, 0, 0, 0);
                        c1 = __builtin_amdgcn_mfma_f32_16x16x32_bf16(afragA[kk], b1, c1, 0, 0, 0);
                        c2 = __builtin_amdgcn_mfma_f32_16x16x32_bf16(afragB[kk], b0, c2, 0, 0, 0);
                        c3 = __builtin_amdgcn_mfma_f32_16x16x32_bf16(afragB[kk], b1, c3, 0, 0, 0);
                    }
#pragma unroll
                    for (int r = 0; r < 4; r++) {
                        bvA[r] = fminf(bvA[r], fminf(fmaxf(xnA[r] - 2.f * c0[r] + yn0, 0.f),
                                                     fmaxf(xnA[r] - 2.f * c1[r] + yn1, 0.f)));
                        bvB[r] = fminf(bvB[r], fminf(fmaxf(xnB[r] - 2.f * c2[r] + yn0, 0.f),
                                                     fmaxf(xnB[r] - 2.f * c3[r] + yn1, 0.f)));
                    }
                } else if (a0) {
                    floatx4 c0 = {0,0,0,0}, c1 = {0,0,0,0};
#pragma unroll
                    for (int kk = 0; kk < 16; kk++) {
                        bf16x8 b0 = *(const bf16x8*)(&Bs[nrow * BSTRIDE + kk * 32 + seg * 8]);
                        bf16x8 b1 = *(const bf16x8*)(&Bs[(nrow + 16) * BSTRIDE + kk * 32 + seg * 8]);
                        c0 = __builtin_amdgcn_mfma_f32_16x16x32_bf16(afragA[kk], b0, c0, 0, 0, 0);
                        c1 = __builtin_amdgcn_mfma_f32_16x16x32_bf16(afragA[kk], b1, c1, 0, 0, 0);
                    }
#pragma unroll
                    for (int r = 0; r < 4; r++)
                        bvA[r] = fminf(bvA[r], fminf(fmaxf(xnA[r] - 2.f * c0[r] + yn0, 0.f),
                                                     fmaxf(xnA[r] - 2.f * c1[r] + yn1, 0.f)));
                } else {
                    floatx4 c2 = {0,0,0,0}, c3 = {0,0,0,0};
#pragma unroll
                    for (int kk = 0; kk < 16; kk++) {
                        bf16x8 b0 = *(const bf16x8*)(&Bs[nrow * BSTRIDE + kk * 32 + seg * 8]);
                        bf16x8 b1 = *(const bf16x8*)(&Bs[(nrow + 16) * BSTRIDE + kk * 32 + seg * 8]);
                        c2 = __builtin_amdgcn_mfma_f32_16x16x32_bf16(afragB[kk], b0, c2, 0, 0, 0);
                        c3 = __builtin_amdgcn_mfma_f32_16x16x32_bf16(afragB[kk], b1, c3, 0, 0, 0);
                    }
#pragma unroll
                    for (int r = 0; r < 4; r++)
                        bvB[r] = fminf(bvB[r], fminf(fmaxf(xnB[r] - 2.f * c2[r] + yn0, 0.f),
                                                     fmaxf(xnB[r] - 2.f * c3[r] + yn1, 0.f)));
                }
            }
        }
    }

    // reduce min over the 16 n-lanes; write both rows
#pragma unroll
    for (int r = 0; r < 4; r++) {
        float v = bvA[r];
        v = fminf(v, __shfl_xor(v, 1, 64));
        v = fminf(v, __shfl_xor(v, 2, 64));
        v = fminf(v, __shfl_xor(v, 4, 64));
        v = fminf(v, __shfl_xor(v, 8, 64));
        bvA[r] = v;
        float u = bvB[r];
        u = fminf(u, __shfl_xor(u, 1, 64));
        u = fminf(u, __shfl_xor(u, 2, 64));
        u = fminf(u, __shfl_xor(u, 4, 64));
        u = fminf(u, __shfl_xor(u, 8, 64));
        bvB[r] = u;
    }
    if ((lane & 15) == 0) {
        int posA = h0 * W1 + w;
        int posB = (h0 + 1) * W1 + w;
#pragma unroll
        for (int r = 0; r < 4; r++) {
            int b = seg * 4 + r;
            best[(size_t)b * (H1 * W1) + posA] = sqrtf(bvA[r]);
            best[(size_t)b * (H1 * W1) + posB] = sqrtf(bvB[r]);
        }
    }
}

// ---------------- fallback: fp32-staging dist (proven R2, 1x4 tile) ----------------
__global__ __launch_bounds__(256) void dist_kernel_f32(
        const float* __restrict__ emb, const float* __restrict__ mb,
        const float* __restrict__ xnorm, const float* __restrict__ ynorm,
        float* __restrict__ best) {
    __shared__ __bf16 Bs[NN * BSTRIDE];
    int bx   = blockIdx.x;
    int h    = bx / 14;
    int w0   = (bx % 14) * 4;
    int tid  = threadIdx.x;
    int wave = tid >> 6;
    int lane = tid & 63;
    int nrow = lane & 15;
    int seg  = lane >> 4;
    int w    = w0 + wave;

    bf16x8 afrag[16];
    const float* ap = emb + ((size_t)(h * W1 + w) * BB + nrow) * CC + seg * 8;
#pragma unroll
    for (int kk = 0; kk < 16; kk++) {
        floatx4 f0 = *(const floatx4*)(ap + kk * 32);
        floatx4 f1 = *(const floatx4*)(ap + kk * 32 + 4);
        bf16x8 v;
        v[0] = (__bf16)f0.x; v[1] = (__bf16)f0.y; v[2] = (__bf16)f0.z; v[3] = (__bf16)f0.w;
        v[4] = (__bf16)f1.x; v[5] = (__bf16)f1.y; v[6] = (__bf16)f1.z; v[7] = (__bf16)f1.w;
        afrag[kk] = v;
    }
    floatx4 xn = *(const floatx4*)(xnorm + (size_t)(h * W1 + w) * BB + seg * 4);
    float bestv[4] = {1e30f, 1e30f, 1e30f, 1e30f};

    for (int d1 = 0; d1 < 5; d1++) {
        int mr = h + d1;
        for (int j = 0; j < 8; j++) {
            int mc = w0 + j;
            const float* bp = mb + (size_t)(mr * MW + mc) * NN * CC;
            __syncthreads();
#pragma unroll
            for (int t = 0; t < 8; t++) {
                int c0 = t * 256 + tid;
                int n  = c0 >> 6;
                int ks = (c0 & 63) << 3;
                floatx4 f0 = *(const floatx4*)(bp + n * CC + ks);
                floatx4 f1 = *(const floatx4*)(bp + n * CC + ks + 4);
                bf16x8 v;
                v[0] = (__bf16)f0.x; v[1] = (__bf16)f0.y; v[2] = (__bf16)f0.z; v[3] = (__bf16)f0.w;
                v[4] = (__bf16)f1.x; v[5] = (__bf16)f1.y; v[6] = (__bf16)f1.z; v[7] = (__bf16)f1.w;
                *(bf16x8*)(&Bs[n * BSTRIDE + ks]) = v;
            }
            __syncthreads();

            int d2 = j - wave;
            if (d2 >= 0 && d2 < 5) {
                float yn0 = ynorm[(size_t)(mr * MW + mc) * NN + nrow];
                float yn1 = ynorm[(size_t)(mr * MW + mc) * NN + nrow + 16];
                floatx4 acc0 = {0,0,0,0};
                floatx4 acc1 = {0,0,0,0};
#pragma unroll
                for (int kk = 0; kk < 16; kk++) {
                    bf16x8 b0 = *(const bf16x8*)(&Bs[nrow * BSTRIDE + kk * 32 + seg * 8]);
                    bf16x8 b1 = *(const bf16x8*)(&Bs[(nrow + 16) * BSTRIDE + kk * 32 + seg * 8]);
                    acc0 = __builtin_amdgcn_mfma_f32_16x16x32_bf16(afrag[kk], b0, acc0, 0, 0, 0);
                    acc1 = __builtin_amdgcn_mfma_f32_16x16x32_bf16(afrag[kk], b1, acc1, 0, 0, 0);
                }
#pragma unroll
                for (int r = 0; r < 4; r++) {
                    float d0  = fmaxf(xn[r] - 2.f * acc0[r] + yn0, 0.f);
                    float d1v = fmaxf(xn[r] - 2.f * acc1[r] + yn1, 0.f);
                    bestv[r] = fminf(bestv[r], fminf(d0, d1v));
                }
            }
        }
    }
#pragma unroll
    for (int r = 0; r < 4; r++) {
        float v = bestv[r];
        v = fminf(v, __shfl_xor(v, 1, 64));
        v = fminf(v, __shfl_xor(v, 2, 64));
        v = fminf(v, __shfl_xor(v, 4, 64));
        v = fminf(v, __shfl_xor(v, 8, 64));
        bestv[r] = v;
    }
    if ((lane & 15) == 0) {
        int pos = h * W1 + w;
#pragma unroll
        for (int r = 0; r < 4; r++) {
            int b = seg * 4 + r;
            best[(size_t)b * (H1 * W1) + pos] = sqrtf(bestv[r]);
        }
    }
}

// ---------------- img = per-batch max ----------------
__global__ void max_kernel(const float* __restrict__ best, float* __restrict__ out) {
    __shared__ float red[256];
    int b = blockIdx.x;
    float m = 0.f;
    for (int i = threadIdx.x; i < H1 * W1; i += 256)
        m = fmaxf(m, best[(size_t)b * (H1 * W1) + i]);
    red[threadIdx.x] = m;
    __syncthreads();
    for (int s = 128; s > 0; s >>= 1) {
        if (threadIdx.x < s) red[threadIdx.x] = fmaxf(red[threadIdx.x], red[threadIdx.x + s]);
        __syncthreads();
    }
    if (threadIdx.x == 0) out[b] = red[0];
}

// ---------------- fused blur: operate on low-res, fold bilinear into taps ----
// blur(resize(best)) is linear in best; evaluate y-pass on low-res columns,
// then x-pass on low-res rows. Deletes the 51 MB `up` intermediate entirely.
struct GaussK { float k[33]; };

__device__ __forceinline__ int refl(int i, int n) {
    i = (i < 0) ? -i : i;
    i = (i > n - 1) ? 2 * (n - 1) - i : i;
    return i;
}

// tmp1[b][y(224)][lx(56)] = sum_u g[u] * lerp_y(best, z=refl(y-16+u))
__global__ void vblur_kernel(const float* __restrict__ best, float* __restrict__ tmp1, GaussK g) {
    int idx = blockIdx.x * 256 + threadIdx.x;
    int lx = idx % W1;
    int y  = (idx / W1) % OH;
    int b  = idx / (W1 * OH);
    const float* p = best + (size_t)b * (H1 * W1);
    float acc = 0.f;
#pragma unroll
    for (int u = 0; u < 33; u++) {
        int z  = refl(y - 16 + u, OH);
        int rz = z & 3;
        float t = 0.125f + 0.25f * (float)((rz + 2) & 3);
        int lo = (z >> 2) + ((rz < 2) ? -1 : 0);
        int hi = min(lo + 1, H1 - 1);
        lo = max(lo, 0);
        acc += g.k[u] * ((1.f - t) * p[lo * W1 + lx] + t * p[hi * W1 + lx]);
    }
    tmp1[idx] = acc;
}

// out[b][y][x(224)] = sum_u g[u] * lerp_x(tmp1[b][y], z=refl(x-16+u))
__global__ void hblur_kernel(const float* __restrict__ tmp1, float* __restrict__ dst, GaussK g) {
    int idx = blockIdx.x * 256 + threadIdx.x;
    int x = idx % OW;
    int y = (idx / OW) % OH;
    int b = idx / (OW * OH);
    const float* p = tmp1 + ((size_t)b * OH + y) * W1;
    float acc = 0.f;
#pragma unroll
    for (int u = 0; u < 33; u++) {
        int z  = refl(x - 16 + u, OW);
        int rz = z & 3;
        float t = 0.125f + 0.25f * (float)((rz + 2) & 3);
        int lo = (z >> 2) + ((rz < 2) ? -1 : 0);
        int hi = min(lo + 1, W1 - 1);
        lo = max(lo, 0);
        acc += g.k[u] * ((1.f - t) * p[lo] + t * p[hi]);
    }
    dst[idx] = acc;
}

extern "C" void kernel_launch(void* const* d_in, const int* in_sizes, int n_in,
                              void* d_out, int out_size, void* d_ws, size_t ws_size,
                              hipStream_t stream) {
    const float* emb = (const float*)d_in[0];
    const float* mbp = (const float*)d_in[1];
    float* ws  = (float*)d_ws;
    float* out = (float*)d_out;

    bool big = ws_size >= F_TOTAL_FLOATS * 4ull;

    float* xnorm = ws + (big ? F_XN_OFF   : S_XN_OFF);
    float* ynorm = ws + (big ? F_YN_OFF   : S_YN_OFF);
    float* best  = ws + (big ? F_BEST_OFF : S_BEST_OFF);
    float* tmp1  = ws + (big ? F_TMP1_OFF : S_TMP1_OFF);

    if (big) {
        __bf16* mbh  = (__bf16*)(ws + MBH_OFF);
        __bf16* embh = (__bf16*)(ws + EMBH_OFF);
        cvt_norm_kernel<<<(H1 * W1 * BB) / 4, 256, 0, stream>>>(emb, embh, xnorm, H1 * W1 * BB);
        cvt_norm_kernel<<<(MH * MW * NN) / 4, 256, 0, stream>>>(mbp, mbh, ynorm, MH * MW * NN);
        dist_kernel_bf16<<<28 * 14, 256, 0, stream>>>(embh, mbh, xnorm, ynorm, best);
    } else {
        cvt_norm_kernel<<<(H1 * W1 * BB) / 4, 256, 0, stream>>>(emb, nullptr, xnorm, H1 * W1 * BB);
        cvt_norm_kernel<<<(MH * MW * NN) / 4, 256, 0, stream>>>(mbp, nullptr, ynorm, MH * MW * NN);
        dist_kernel_f32<<<H1 * 14, 256, 0, stream>>>(emb, mbp, xnorm, ynorm, best);
    }

    max_kernel<<<BB, 256, 0, stream>>>(best, out);

    GaussK g;
    {
        double wsum = 0.0, wd[33];
        for (int u = 0; u < 33; u++) {
            double xk = (u - 16) / 4.0;
            wd[u] = exp(-0.5 * xk * xk);
            wsum += wd[u];
        }
        for (int u = 0; u < 33; u++) g.k[u] = (float)(wd[u] / wsum);
    }
    vblur_kernel<<<(BB * OH * W1) / 256, 256, 0, stream>>>(best, tmp1, g);
    hblur_kernel<<<(BB * OH * OW) / 256, 256, 0, stream>>>(tmp1, out + 16, g);
}